// Round 3
// baseline (7845.665 us; speedup 1.0000x reference)
//
#include <hip/hip_runtime.h>

// NGCF forward on gfx950 — round 3: bucketed SpMM (no row-level CSR).
//
// Edges are partitioned into 1172 buckets of 128 consecutive rows. Bucket
// tickets advance monotonically -> scatter writes are sequential per bucket
// (no 8x line amplification like the row-level ticket scatter of R2).
// SpMM: one workgroup per bucket, 128x64 f32 accumulator in LDS (32 KB),
// LDS float atomics, one coalesced write per row. Graph topology work
// (hist/scan/scatter) is redone every launch (ws is re-poisoned).

#define EMB 64

constexpr int kNUsers   = 100000;
constexpr int kNItems   = 50000;
constexpr int kNNodes   = 150000;
constexpr int kNEdges   = 4800000;
constexpr int kBatch    = 16384;
constexpr int kLayers   = 3;
constexpr int kRowsPB   = 128;                 // rows per bucket (r >> 7)
constexpr int kNB       = (kNNodes + kRowsPB - 1) / kRowsPB;   // 1172
constexpr int kEPW      = 16;                  // fallback atomic spmm only

__device__ __forceinline__ float f4c(const float4& v, int i) {
  return ((const float*)&v)[i];
}
__device__ __forceinline__ float4 f4fma(float s, float4 w, float4 a) {
  a.x = fmaf(s, w.x, a.x);
  a.y = fmaf(s, w.y, a.y);
  a.z = fmaf(s, w.z, a.z);
  a.w = fmaf(s, w.w, a.w);
  return a;
}
__device__ __forceinline__ float lrelu(float x) { return x > 0.f ? x : 0.2f * x; }

// ---------------------------------------------------------------------------
// Bucket histogram: LDS pre-aggregation, then one merge per bucket per block.
// ---------------------------------------------------------------------------
__global__ __launch_bounds__(256) void hist_buckets(
    const int* __restrict__ rows, int* __restrict__ bucketCnt)
{
  __shared__ int h[kNB];
  const int tid = threadIdx.x;
  for (int i = tid; i < kNB; i += 256) h[i] = 0;
  __syncthreads();
  for (int e = blockIdx.x * 256 + tid; e < kNEdges; e += gridDim.x * 256)
    atomicAdd(&h[rows[e] >> 7], 1);
  __syncthreads();
  for (int i = tid; i < kNB; i += 256) {
    const int c = h[i];
    if (c) atomicAdd(&bucketCnt[i], c);
  }
}

// Single-wave exclusive scan over kNB bucket counts; zeroes cursors.
__global__ __launch_bounds__(64) void scan_buckets(
    const int* __restrict__ bucketCnt, int* __restrict__ bucketStart,
    int* __restrict__ bucketCur)
{
  const int lane = threadIdx.x;
  int running = 0;
  for (int base = 0; base < kNB; base += 64) {
    const int i = base + lane;
    const int c = (i < kNB) ? bucketCnt[i] : 0;
    int v = c;
#pragma unroll
    for (int off = 1; off < 64; off <<= 1) {
      const int n = __shfl_up(v, off, 64);
      if (lane >= off) v += n;
    }
    if (i < kNB) { bucketStart[i] = running + v - c; bucketCur[i] = 0; }
    running += __shfl(v, 63, 64);
  }
  if (lane == 0) bucketStart[kNB] = running;   // == kNEdges
}

// Ticket scatter into bucket-segmented edge array.
// Payload: x = (row&127)<<18 | col  (col < 2^18), y = bits(val).
__global__ __launch_bounds__(256) void scatter_bucket(
    const int* __restrict__ rows, const int* __restrict__ cols,
    const float* __restrict__ vals, const int* __restrict__ bucketStart,
    int* __restrict__ bucketCur, int2* __restrict__ edgeS)
{
  const int e = blockIdx.x * 256 + threadIdx.x;
  if (e >= kNEdges) return;
  const int r = rows[e];
  const int b = r >> 7;
  const int idx = bucketStart[b] + atomicAdd(&bucketCur[b], 1);
  edgeS[idx] = make_int2(((r & 127) << 18) | cols[e], __float_as_int(vals[e]));
}

// ---------------------------------------------------------------------------
// Bucketed SpMM: one workgroup per bucket; 128x64 f32 LDS accumulator;
// lane = dim; LDS float atomics (waves may collide on a row).
// ---------------------------------------------------------------------------
__global__ __launch_bounds__(256) void spmm_bucket(
    const float* __restrict__ cur, const int* __restrict__ bucketStart,
    const int2* __restrict__ edgeS, float* __restrict__ nbuf)
{
  __shared__ float acc[kRowsPB * EMB];          // 32 KB
  const int tid  = threadIdx.x;
  const int lane = tid & 63;
  const int wid  = tid >> 6;
  const int b    = blockIdx.x;

  for (int i = tid; i < kRowsPB * EMB / 4; i += 256)
    ((float4*)acc)[i] = make_float4(0.f, 0.f, 0.f, 0.f);
  __syncthreads();

  const int start = bucketStart[b];
  const int end   = bucketStart[b + 1];

  int e = start + wid;
  for (; e + 4 < end; e += 8) {                 // 2 edges per iter per wave
    const int2 cv0 = edgeS[e];
    const int2 cv1 = edgeS[e + 4];
    const int rl0 = cv0.x >> 18, c0 = cv0.x & 0x3ffff;
    const int rl1 = cv1.x >> 18, c1 = cv1.x & 0x3ffff;
    const float x0 = cur[(size_t)c0 * EMB + lane];
    const float x1 = cur[(size_t)c1 * EMB + lane];
    atomicAdd(&acc[rl0 * EMB + lane], __int_as_float(cv0.y) * x0);
    atomicAdd(&acc[rl1 * EMB + lane], __int_as_float(cv1.y) * x1);
  }
  if (e < end) {
    const int2 cv = edgeS[e];
    const int rl = cv.x >> 18, c = cv.x & 0x3ffff;
    atomicAdd(&acc[rl * EMB + lane], __int_as_float(cv.y) * cur[(size_t)c * EMB + lane]);
  }
  __syncthreads();

  const int rowsHere = min(kRowsPB, kNNodes - (b << 7));
  float4* __restrict__ dst = (float4*)(nbuf + (size_t)(b << 7) * EMB);
  const int total = rowsHere * EMB / 4;
  for (int i = tid; i < total; i += 256) dst[i] = ((const float4*)acc)[i];
}

// ---------------------------------------------------------------------------
// Fallback atomic SpMM (only if ws too small for bucket buffers).
// ---------------------------------------------------------------------------
__global__ __launch_bounds__(256) void spmm_atomic(
    const float* __restrict__ cur, const int* __restrict__ rows,
    const int* __restrict__ cols, const float* __restrict__ vals,
    float* __restrict__ nbuf)
{
  const int lane = threadIdx.x & 63;
  int wv = (blockIdx.x << 2) | (threadIdx.x >> 6);
  wv = __builtin_amdgcn_readfirstlane(wv);
  int e0 = wv * kEPW;
  int e1 = e0 + kEPW;
  if (e1 > kNEdges) e1 = kNEdges;
  for (int e = e0; e < e1; ++e) {
    const int   c = cols[e];
    const int   r = rows[e];
    atomicAdd(nbuf + (size_t)r * EMB + lane, vals[e] * cur[(size_t)c * EMB + lane]);
  }
}

// ---------------------------------------------------------------------------
// Fused per-node transform (unchanged from R2).
// ---------------------------------------------------------------------------
__global__ __launch_bounds__(256) void transform_inplace(
    float* __restrict__ cur, const float* __restrict__ nbuf,
    const float* __restrict__ W1, const float* __restrict__ b1,
    const float* __restrict__ W2, const float* __restrict__ b2)
{
  const int node = blockIdx.x * 256 + threadIdx.x;
  if (node >= kNNodes) return;

  const float4* __restrict__ xr  = (const float4*)(cur  + (size_t)node * EMB);
  const float4* __restrict__ nr  = (const float4*)(nbuf + (size_t)node * EMB);
  const float4* __restrict__ b1v = (const float4*)b1;
  const float4* __restrict__ b2v = (const float4*)b2;

  float4 acc1[16], acc2[16];
#pragma unroll
  for (int j = 0; j < 16; ++j) { acc1[j] = b1v[j]; acc2[j] = b2v[j]; }

#pragma unroll 2
  for (int k4 = 0; k4 < 16; ++k4) {
    const float4 xv = xr[k4];
    const float4 nv = nr[k4];
#pragma unroll
    for (int kk = 0; kk < 4; ++kk) {
      const int k = 4 * k4 + kk;
      const float xs = f4c(xv, kk);
      const float ns = f4c(nv, kk);
      const float4* __restrict__ w1r = (const float4*)(W1 + k * EMB);
      const float4* __restrict__ w2r = (const float4*)(W2 + k * EMB);
#pragma unroll
      for (int j = 0; j < 16; ++j) {
        acc1[j] = f4fma(xs, w1r[j], acc1[j]);
        acc2[j] = f4fma(ns, w2r[j], acc2[j]);
      }
    }
  }

#pragma unroll
  for (int k4 = 0; k4 < 16; ++k4) {
    const float4 xv = xr[k4];
    const float4 tv = acc2[k4];
#pragma unroll
    for (int kk = 0; kk < 4; ++kk) {
      const float ms = f4c(tv, kk) * f4c(xv, kk);
      const float4* __restrict__ w2r = (const float4*)(W2 + (4 * k4 + kk) * EMB);
#pragma unroll
      for (int j = 0; j < 16; ++j) acc1[j] = f4fma(ms, w2r[j], acc1[j]);
    }
  }

  float4* __restrict__ outp = (float4*)(cur + (size_t)node * EMB);
#pragma unroll
  for (int j = 0; j < 16; ++j) {
    float4 r;
    r.x = lrelu(acc1[j].x + acc2[j].x + b2v[j].x);
    r.y = lrelu(acc1[j].y + acc2[j].y + b2v[j].y);
    r.z = lrelu(acc1[j].z + acc2[j].z + b2v[j].z);
    r.w = lrelu(acc1[j].w + acc2[j].w + b2v[j].w);
    outp[j] = r;
  }
}

// ---------------------------------------------------------------------------
__global__ __launch_bounds__(256) void gather_out(
    const float* __restrict__ cur, const int* __restrict__ users,
    const int* __restrict__ pos, const int* __restrict__ neg,
    float* __restrict__ out, int layer)
{
  const int t    = blockIdx.x * 256 + threadIdx.x;
  const int lane = t & 63;
  const int rid  = t >> 6;
  if (rid >= 3 * kBatch) return;
  const int seg = rid / kBatch;
  const int b   = rid - seg * kBatch;
  int idx;
  if (seg == 0)      idx = users[b];
  else if (seg == 1) idx = pos[b] + kNUsers;
  else               idx = neg[b] + kNUsers;
  out[(size_t)rid * 256 + layer * EMB + lane] = cur[(size_t)idx * EMB + lane];
}

// ---------------------------------------------------------------------------
extern "C" void kernel_launch(void* const* d_in, const int* in_sizes, int n_in,
                              void* d_out, int out_size, void* d_ws, size_t ws_size,
                              hipStream_t stream) {
  const int*   users    = (const int*)d_in[0];
  const int*   pos      = (const int*)d_in[1];
  const int*   neg      = (const int*)d_in[2];
  const int*   rows     = (const int*)d_in[3];
  const int*   cols     = (const int*)d_in[4];
  const float* vals     = (const float*)d_in[5];
  const float* user_emb = (const float*)d_in[6];
  const float* item_emb = (const float*)d_in[7];
  const float* W1s      = (const float*)d_in[8];
  const float* b1s      = (const float*)d_in[9];
  const float* W2s      = (const float*)d_in[10];
  const float* b2s      = (const float*)d_in[11];
  float* out = (float*)d_out;

  // ws layout
  const size_t nodeF = (size_t)kNNodes * EMB;               // 9.6M floats
  float* cur  = (float*)d_ws;                               // 38.4 MB
  float* nbuf = cur + nodeF;                                // 38.4 MB
  int2*  edgeS       = (int2*)(nbuf + nodeF);               // 38.4 MB
  int*   bucketStart = (int*)(edgeS + kNEdges);             // (kNB+1) ints
  int*   bucketCur   = bucketStart + (kNB + 1);
  int*   bucketCnt   = bucketCur + kNB;
  const size_t needed = (size_t)((char*)(bucketCnt + kNB) - (char*)d_ws);
  const bool useBuckets = ws_size >= needed;

  hipMemcpyAsync(cur, user_emb, (size_t)kNUsers * EMB * sizeof(float),
                 hipMemcpyDeviceToDevice, stream);
  hipMemcpyAsync(cur + (size_t)kNUsers * EMB, item_emb,
                 (size_t)kNItems * EMB * sizeof(float),
                 hipMemcpyDeviceToDevice, stream);

  const dim3 blk(256);
  const int gblocks = (3 * kBatch * EMB + 255) / 256;             // 12288
  const int eblocks = (kNEdges + 255) / 256;                      // 18750
  const int tblocks = (kNNodes + 255) / 256;                      // 586

  if (useBuckets) {
    hipMemsetAsync(bucketCnt, 0, kNB * sizeof(int), stream);
    hist_buckets<<<1024, blk, 0, stream>>>(rows, bucketCnt);
    scan_buckets<<<1, 64, 0, stream>>>(bucketCnt, bucketStart, bucketCur);
    scatter_bucket<<<eblocks, blk, 0, stream>>>(rows, cols, vals, bucketStart,
                                                bucketCur, edgeS);
  }

  gather_out<<<gblocks, blk, 0, stream>>>(cur, users, pos, neg, out, 0);

  for (int L = 0; L < kLayers; ++L) {
    if (useBuckets) {
      spmm_bucket<<<kNB, blk, 0, stream>>>(cur, bucketStart, edgeS, nbuf);
    } else {
      hipMemsetAsync(nbuf, 0, nodeF * sizeof(float), stream);
      const int sblocks = (((kNEdges + kEPW - 1) / kEPW) + 3) / 4;
      spmm_atomic<<<sblocks, blk, 0, stream>>>(cur, rows, cols, vals, nbuf);
    }
    transform_inplace<<<tblocks, blk, 0, stream>>>(
        cur, nbuf, W1s + L * EMB * EMB, b1s + L * EMB,
        W2s + L * EMB * EMB, b2s + L * EMB);
    gather_out<<<gblocks, blk, 0, stream>>>(cur, users, pos, neg, out, L + 1);
  }
}

// Round 4
// 1658.028 us; speedup vs baseline: 4.7319x; 4.7319x over previous
//
#include <hip/hip_runtime.h>

// NGCF forward on gfx950 — round 4: R2 CSR structure + parallel scan +
// unroll-4 SpMM. (R3's coarse-bucket tickets serialized 4096-deep atomic
// chains per counter — reverted to per-row tickets, 32 edges/counter.)
//
// Per launch:
//   cur = concat(user_emb, item_emb)           [150000 x 64] f32
//   rowCnt = histogram(rows)                   (atomics, 600 KB, L2-resident)
//   rowPtr = exclusive_scan(rowCnt)            (3-kernel parallel scan)
//   edgeS[rowPtr[r]+ticket] = (col,val)        (per-row atomic tickets)
//   for L in 0..2:
//     spmm_csr  : nbuf[r] = sum val*cur[col]   (wave/row, 4-way unrolled)
//     transform : cur = leaky(cur@W1+b1 + t + (t*cur)@W2+b2), t=nbuf@W2+b2
//     gather layer slice

#define EMB 64

constexpr int kNUsers = 100000;
constexpr int kNItems = 50000;
constexpr int kNNodes = 150000;
constexpr int kNEdges = 4800000;
constexpr int kBatch  = 16384;
constexpr int kLayers = 3;
constexpr int kScanB  = (kNNodes + 255) / 256;   // 586 scan blocks
constexpr int kEPW    = 16;                      // fallback only

__device__ __forceinline__ float f4c(const float4& v, int i) {
  return ((const float*)&v)[i];
}
__device__ __forceinline__ float4 f4fma(float s, float4 w, float4 a) {
  a.x = fmaf(s, w.x, a.x);
  a.y = fmaf(s, w.y, a.y);
  a.z = fmaf(s, w.z, a.z);
  a.w = fmaf(s, w.w, a.w);
  return a;
}
__device__ __forceinline__ float lrelu(float x) { return x > 0.f ? x : 0.2f * x; }

// ---------------------------------------------------------------------------
// CSR build
// ---------------------------------------------------------------------------
__global__ __launch_bounds__(256) void hist_rows(
    const int* __restrict__ rows, int* __restrict__ rowCnt)
{
  const int e = blockIdx.x * 256 + threadIdx.x;
  if (e < kNEdges) atomicAdd(&rowCnt[rows[e]], 1);
}

// scan1: per-block (256-elem) exclusive scan; emits block totals; zeroes rowCnt.
__global__ __launch_bounds__(256) void scan1(
    int* __restrict__ rowCnt, int* __restrict__ rowPtr,
    int* __restrict__ blockSums)
{
  __shared__ int wsum[4];
  const int tid  = threadIdx.x;
  const int lane = tid & 63;
  const int wid  = tid >> 6;
  const int i    = blockIdx.x * 256 + tid;
  const int cnt  = (i < kNNodes) ? rowCnt[i] : 0;
  int v = cnt;
#pragma unroll
  for (int off = 1; off < 64; off <<= 1) {
    const int n = __shfl_up(v, off, 64);
    if (lane >= off) v += n;
  }
  if (lane == 63) wsum[wid] = v;
  __syncthreads();
  if (tid == 0) {
    int s = 0;
#pragma unroll
    for (int w = 0; w < 4; ++w) { const int t = wsum[w]; wsum[w] = s; s += t; }
    blockSums[blockIdx.x] = s;
  }
  __syncthreads();
  if (i < kNNodes) {
    rowPtr[i] = wsum[wid] + v - cnt;   // block-local exclusive
    rowCnt[i] = 0;                     // reset for ticket pass
  }
}

// scan2: exclusive scan of the 586 block sums, single workgroup.
__global__ __launch_bounds__(1024) void scan2(int* __restrict__ blockSums)
{
  __shared__ int wsum[16];
  const int tid  = threadIdx.x;
  const int lane = tid & 63;
  const int wid  = tid >> 6;
  const int cnt  = (tid < kScanB) ? blockSums[tid] : 0;
  int v = cnt;
#pragma unroll
  for (int off = 1; off < 64; off <<= 1) {
    const int n = __shfl_up(v, off, 64);
    if (lane >= off) v += n;
  }
  if (lane == 63) wsum[wid] = v;
  __syncthreads();
  if (tid == 0) {
    int s = 0;
#pragma unroll
    for (int w = 0; w < 16; ++w) { const int t = wsum[w]; wsum[w] = s; s += t; }
  }
  __syncthreads();
  if (tid < kScanB) blockSums[tid] = wsum[wid] + v - cnt;   // exclusive
}

// scan3: add block offsets; set rowPtr[kNNodes].
__global__ __launch_bounds__(256) void scan3(
    int* __restrict__ rowPtr, const int* __restrict__ blockSums)
{
  const int i = blockIdx.x * 256 + threadIdx.x;
  if (i < kNNodes) rowPtr[i] += blockSums[blockIdx.x];
  if (i == 0) rowPtr[kNNodes] = kNEdges;
}

__global__ __launch_bounds__(256) void scatter_edges(
    const int* __restrict__ rows, const int* __restrict__ cols,
    const float* __restrict__ vals, const int* __restrict__ rowPtr,
    int* __restrict__ rowCnt, int2* __restrict__ edgeS)
{
  const int e = blockIdx.x * 256 + threadIdx.x;
  if (e >= kNEdges) return;
  const int r   = rows[e];
  const int idx = rowPtr[r] + atomicAdd(&rowCnt[r], 1);
  edgeS[idx] = make_int2(cols[e], __float_as_int(vals[e]));
}

// ---------------------------------------------------------------------------
// CSR SpMM: one wave per row, lane = dim, 4 accumulators / 4 gathers in flight.
// Edge loads are wave-uniform (scalar path); gathers are 256 B coalesced.
// ---------------------------------------------------------------------------
__global__ __launch_bounds__(256) void spmm_csr(
    const float* __restrict__ cur, const int* __restrict__ rowPtr,
    const int2* __restrict__ edgeS, float* __restrict__ nbuf)
{
  const int lane = threadIdx.x & 63;
  const int r = (blockIdx.x << 2) | (threadIdx.x >> 6);
  if (r >= kNNodes) return;
  const int start = __builtin_amdgcn_readfirstlane(rowPtr[r]);
  const int end   = __builtin_amdgcn_readfirstlane(rowPtr[r + 1]);
  float a0 = 0.f, a1 = 0.f, a2 = 0.f, a3 = 0.f;
  int e = start;
  for (; e + 4 <= end; e += 4) {
    const int2 cv0 = edgeS[e];
    const int2 cv1 = edgeS[e + 1];
    const int2 cv2 = edgeS[e + 2];
    const int2 cv3 = edgeS[e + 3];
    const float x0 = cur[(size_t)cv0.x * EMB + lane];
    const float x1 = cur[(size_t)cv1.x * EMB + lane];
    const float x2 = cur[(size_t)cv2.x * EMB + lane];
    const float x3 = cur[(size_t)cv3.x * EMB + lane];
    a0 = fmaf(__int_as_float(cv0.y), x0, a0);
    a1 = fmaf(__int_as_float(cv1.y), x1, a1);
    a2 = fmaf(__int_as_float(cv2.y), x2, a2);
    a3 = fmaf(__int_as_float(cv3.y), x3, a3);
  }
  for (; e < end; ++e) {
    const int2 cv = edgeS[e];
    a0 = fmaf(__int_as_float(cv.y), cur[(size_t)cv.x * EMB + lane], a0);
  }
  nbuf[(size_t)r * EMB + lane] = (a0 + a1) + (a2 + a3);
}

// ---------------------------------------------------------------------------
// Fallback atomic SpMM (ws too small).
// ---------------------------------------------------------------------------
__global__ __launch_bounds__(256) void spmm_atomic(
    const float* __restrict__ cur, const int* __restrict__ rows,
    const int* __restrict__ cols, const float* __restrict__ vals,
    float* __restrict__ nbuf)
{
  const int lane = threadIdx.x & 63;
  int wv = (blockIdx.x << 2) | (threadIdx.x >> 6);
  wv = __builtin_amdgcn_readfirstlane(wv);
  int e0 = wv * kEPW;
  int e1 = e0 + kEPW;
  if (e1 > kNEdges) e1 = kNEdges;
  for (int e = e0; e < e1; ++e) {
    atomicAdd(nbuf + (size_t)rows[e] * EMB + lane,
              vals[e] * cur[(size_t)cols[e] * EMB + lane]);
  }
}

// ---------------------------------------------------------------------------
// Fused per-node transform (unchanged).
// ---------------------------------------------------------------------------
__global__ __launch_bounds__(256) void transform_inplace(
    float* __restrict__ cur, const float* __restrict__ nbuf,
    const float* __restrict__ W1, const float* __restrict__ b1,
    const float* __restrict__ W2, const float* __restrict__ b2)
{
  const int node = blockIdx.x * 256 + threadIdx.x;
  if (node >= kNNodes) return;

  const float4* __restrict__ xr  = (const float4*)(cur  + (size_t)node * EMB);
  const float4* __restrict__ nr  = (const float4*)(nbuf + (size_t)node * EMB);
  const float4* __restrict__ b1v = (const float4*)b1;
  const float4* __restrict__ b2v = (const float4*)b2;

  float4 acc1[16], acc2[16];
#pragma unroll
  for (int j = 0; j < 16; ++j) { acc1[j] = b1v[j]; acc2[j] = b2v[j]; }

#pragma unroll 2
  for (int k4 = 0; k4 < 16; ++k4) {
    const float4 xv = xr[k4];
    const float4 nv = nr[k4];
#pragma unroll
    for (int kk = 0; kk < 4; ++kk) {
      const int k = 4 * k4 + kk;
      const float xs = f4c(xv, kk);
      const float ns = f4c(nv, kk);
      const float4* __restrict__ w1r = (const float4*)(W1 + k * EMB);
      const float4* __restrict__ w2r = (const float4*)(W2 + k * EMB);
#pragma unroll
      for (int j = 0; j < 16; ++j) {
        acc1[j] = f4fma(xs, w1r[j], acc1[j]);
        acc2[j] = f4fma(ns, w2r[j], acc2[j]);
      }
    }
  }

#pragma unroll
  for (int k4 = 0; k4 < 16; ++k4) {
    const float4 xv = xr[k4];
    const float4 tv = acc2[k4];
#pragma unroll
    for (int kk = 0; kk < 4; ++kk) {
      const float ms = f4c(tv, kk) * f4c(xv, kk);
      const float4* __restrict__ w2r = (const float4*)(W2 + (4 * k4 + kk) * EMB);
#pragma unroll
      for (int j = 0; j < 16; ++j) acc1[j] = f4fma(ms, w2r[j], acc1[j]);
    }
  }

  float4* __restrict__ outp = (float4*)(cur + (size_t)node * EMB);
#pragma unroll
  for (int j = 0; j < 16; ++j) {
    float4 r;
    r.x = lrelu(acc1[j].x + acc2[j].x + b2v[j].x);
    r.y = lrelu(acc1[j].y + acc2[j].y + b2v[j].y);
    r.z = lrelu(acc1[j].z + acc2[j].z + b2v[j].z);
    r.w = lrelu(acc1[j].w + acc2[j].w + b2v[j].w);
    outp[j] = r;
  }
}

// ---------------------------------------------------------------------------
__global__ __launch_bounds__(256) void gather_out(
    const float* __restrict__ cur, const int* __restrict__ users,
    const int* __restrict__ pos, const int* __restrict__ neg,
    float* __restrict__ out, int layer)
{
  const int t    = blockIdx.x * 256 + threadIdx.x;
  const int lane = t & 63;
  const int rid  = t >> 6;
  if (rid >= 3 * kBatch) return;
  const int seg = rid / kBatch;
  const int b   = rid - seg * kBatch;
  int idx;
  if (seg == 0)      idx = users[b];
  else if (seg == 1) idx = pos[b] + kNUsers;
  else               idx = neg[b] + kNUsers;
  out[(size_t)rid * 256 + layer * EMB + lane] = cur[(size_t)idx * EMB + lane];
}

// ---------------------------------------------------------------------------
extern "C" void kernel_launch(void* const* d_in, const int* in_sizes, int n_in,
                              void* d_out, int out_size, void* d_ws, size_t ws_size,
                              hipStream_t stream) {
  const int*   users    = (const int*)d_in[0];
  const int*   pos      = (const int*)d_in[1];
  const int*   neg      = (const int*)d_in[2];
  const int*   rows     = (const int*)d_in[3];
  const int*   cols     = (const int*)d_in[4];
  const float* vals     = (const float*)d_in[5];
  const float* user_emb = (const float*)d_in[6];
  const float* item_emb = (const float*)d_in[7];
  const float* W1s      = (const float*)d_in[8];
  const float* b1s      = (const float*)d_in[9];
  const float* W2s      = (const float*)d_in[10];
  const float* b2s      = (const float*)d_in[11];
  float* out = (float*)d_out;

  const size_t nodeF = (size_t)kNNodes * EMB;
  float* cur  = (float*)d_ws;                               // 38.4 MB
  float* nbuf = cur + nodeF;                                // 38.4 MB
  int2*  edgeS     = (int2*)(nbuf + nodeF);                 // 38.4 MB
  int*   rowPtr    = (int*)(edgeS + kNEdges);               // 600 KB (+1)
  int*   rowCnt    = rowPtr + (kNNodes + 1);                // 600 KB
  int*   blockSums = rowCnt + kNNodes;                      // 2.3 KB
  const size_t needed = (size_t)((char*)(blockSums + kScanB) - (char*)d_ws);
  const bool useCsr = ws_size >= needed;

  hipMemcpyAsync(cur, user_emb, (size_t)kNUsers * EMB * sizeof(float),
                 hipMemcpyDeviceToDevice, stream);
  hipMemcpyAsync(cur + (size_t)kNUsers * EMB, item_emb,
                 (size_t)kNItems * EMB * sizeof(float),
                 hipMemcpyDeviceToDevice, stream);

  const dim3 blk(256);
  const int gblocks = (3 * kBatch * EMB + 255) / 256;       // 12288
  const int eblocks = (kNEdges + 255) / 256;                // 18750
  const int rblocks = (kNNodes + 3) / 4;                    // 37500
  const int tblocks = (kNNodes + 255) / 256;                // 586

  if (useCsr) {
    hipMemsetAsync(rowCnt, 0, (size_t)kNNodes * sizeof(int), stream);
    hist_rows<<<eblocks, blk, 0, stream>>>(rows, rowCnt);
    scan1<<<kScanB, blk, 0, stream>>>(rowCnt, rowPtr, blockSums);
    scan2<<<1, 1024, 0, stream>>>(blockSums);
    scan3<<<kScanB, blk, 0, stream>>>(rowPtr, blockSums);
    scatter_edges<<<eblocks, blk, 0, stream>>>(rows, cols, vals, rowPtr,
                                               rowCnt, edgeS);
  }

  gather_out<<<gblocks, blk, 0, stream>>>(cur, users, pos, neg, out, 0);

  for (int L = 0; L < kLayers; ++L) {
    if (useCsr) {
      spmm_csr<<<rblocks, blk, 0, stream>>>(cur, rowPtr, edgeS, nbuf);
    } else {
      hipMemsetAsync(nbuf, 0, nodeF * sizeof(float), stream);
      const int sblocks = (((kNEdges + kEPW - 1) / kEPW) + 3) / 4;
      spmm_atomic<<<sblocks, blk, 0, stream>>>(cur, rows, cols, vals, nbuf);
    }
    transform_inplace<<<tblocks, blk, 0, stream>>>(
        cur, nbuf, W1s + L * EMB * EMB, b1s + L * EMB,
        W2s + L * EMB * EMB, b2s + L * EMB);
    gather_out<<<gblocks, blk, 0, stream>>>(cur, users, pos, neg, out, L + 1);
  }
}